// Round 1
// baseline (1046.741 us; speedup 1.0000x reference)
//
#include <hip/hip_runtime.h>
#include <hip/hip_bf16.h>

#define NVOX 200000
#define NK   125
#define GRID_LIN (128 * 128 * 128)

// workspace layout (bytes)
#define WT_OFF    0                      // 125*64*64*2 = 1,024,000
#define FB_OFF    (1u << 20)             // (N+1)*128   = 25,600,128
#define IDX_OFF   27262976u              // 2M * 4      = 8,388,608
#define STATS_OFF 35651584u              // 128 * 4

typedef short bf16x8 __attribute__((ext_vector_type(8)));
typedef float f32x4  __attribute__((ext_vector_type(4)));
typedef unsigned short u16x4 __attribute__((ext_vector_type(4)));

static __device__ __forceinline__ unsigned short f2bf(float f) {
    union { float f; unsigned int u; } v; v.f = f;
    unsigned int u = v.u;
    return (unsigned short)((u + 0x7FFFu + ((u >> 16) & 1u)) >> 16);   // RNE
}

// W [125][ci][co] f32  ->  wt [125][co][ci] bf16
__global__ __launch_bounds__(256) void wconv_kernel(const float* __restrict__ Wt,
                                                    unsigned short* __restrict__ wt) {
    int i = blockIdx.x * 256 + threadIdx.x;
    if (i >= NK * 4096) return;
    int k = i >> 12, r = i & 4095;
    int co = r >> 6, ci = r & 63;
    wt[i] = f2bf(Wt[(k << 12) + (ci << 6) + co]);
}

// feats f32 -> bf16, plus one zero row at index NVOX
__global__ __launch_bounds__(256) void fconv_kernel(const float* __restrict__ feats,
                                                    unsigned short* __restrict__ fb) {
    int i = blockIdx.x * 256 + threadIdx.x;
    if (i < NVOX * 16) {
        f32x4 f = *(const f32x4*)(feats + (size_t)i * 4);
        u16x4 u;
        u[0] = f2bf(f[0]); u[1] = f2bf(f[1]); u[2] = f2bf(f[2]); u[3] = f2bf(f[3]);
        *(u16x4*)(fb + (size_t)i * 4) = u;
    } else if (i < NVOX * 16 + 16) {
        u16x4 z = (u16x4)0;
        *(u16x4*)(fb + (size_t)i * 4) = z;
    }
}

__global__ __launch_bounds__(256) void scatter_kernel(const int* __restrict__ coords,
                                                      int* __restrict__ idx_map) {
    int p = blockIdx.x * 256 + threadIdx.x;
    if (p < NVOX) {
        int z = coords[p * 3 + 0], y = coords[p * 3 + 1], x = coords[p * 3 + 2];
        idx_map[(z << 14) | (y << 7) | x] = p;
    }
}

// Implicit-GEMM conv: block = 4 waves, each wave = 64 vox x 64 cout tile.
// D[co][vox] = sum_k W_k[co][ci] * F[ci][vox];  A = W (L2), B = gathered feat rows.
__global__ __launch_bounds__(256, 3) void conv_kernel(
    const int* __restrict__ coords, const unsigned short* __restrict__ fb,
    const unsigned short* __restrict__ wt, const int* __restrict__ idx_map,
    float* __restrict__ out, float* __restrict__ stats) {
    const int tid  = threadIdx.x;
    const int wave = tid >> 6;
    const int lane = tid & 63;
    const int g    = lane >> 4;
    const int l15  = lane & 15;
    const int vbase = blockIdx.x * 256 + wave * 64;

    // this lane computes the neighbor index for voxel vbase + lane
    const int vj = vbase + lane;
    int z = -1000, y = -1000, x = -1000;
    if (vj < NVOX) {
        z = coords[vj * 3 + 0];
        y = coords[vj * 3 + 1];
        x = coords[vj * 3 + 2];
    }

    f32x4 acc[4][4];   // [a = co-tile][b = vox-tile]
#pragma unroll
    for (int a = 0; a < 4; ++a)
#pragma unroll
        for (int b = 0; b < 4; ++b) acc[a][b] = (f32x4)0.0f;

    const char* fbp = (const char*)fb;
    const char* wp  = (const char*)wt;
    int dz = -2, dy = -2, dx = -2;
    for (int k = 0; k < NK; ++k) {
        int nz = z + dz, ny = y + dy, nx = x + dx;
        int j = NVOX;  // zero row
        if (((unsigned)nz < 128u) && ((unsigned)ny < 128u) && ((unsigned)nx < 128u)) {
            int t = idx_map[(nz << 14) | (ny << 7) | nx];
            if (t >= 0) j = t;
        }
        int jt[4];
#pragma unroll
        for (int t = 0; t < 4; ++t) jt[t] = __shfl(j, t * 16 + l15, 64);

#pragma unroll
        for (int s = 0; s < 2; ++s) {
            bf16x8 afrag[4], bfrag[4];
#pragma unroll
            for (int a = 0; a < 4; ++a)
                afrag[a] = *(const bf16x8*)(wp + (((a * 16 + l15) << 7) + (g << 4) + (s << 6)));
#pragma unroll
            for (int t = 0; t < 4; ++t)
                bfrag[t] = *(const bf16x8*)(fbp + (((size_t)(unsigned)jt[t] << 7) + (g << 4) + (s << 6)));
#pragma unroll
            for (int a = 0; a < 4; ++a)
#pragma unroll
                for (int b = 0; b < 4; ++b)
                    acc[a][b] = __builtin_amdgcn_mfma_f32_16x16x32_bf16(afrag[a], bfrag[b], acc[a][b], 0, 0, 0);
        }
        wp += 8192;
        if (++dx == 3) { dx = -2; if (++dy == 3) { dy = -2; ++dz; } }
    }

    // store conv result (pre-BN, bias cancels under train-mode BN)
#pragma unroll
    for (int b = 0; b < 4; ++b) {
        int v = vbase + b * 16 + l15;
        if (v < NVOX) {
#pragma unroll
            for (int a = 0; a < 4; ++a)
                *(f32x4*)(out + (size_t)v * 64 + a * 16 + g * 4) = acc[a][b];
        }
    }

    // BN batch-stat partials: per-channel sum and sumsq over this wave's 64 voxels
    float s1[16], s2[16];
#pragma unroll
    for (int a = 0; a < 4; ++a)
#pragma unroll
        for (int r = 0; r < 4; ++r) {
            float s = 0.f, q = 0.f;
#pragma unroll
            for (int b = 0; b < 4; ++b) { float xv = acc[a][b][r]; s += xv; q += xv * xv; }
            s1[a * 4 + r] = s; s2[a * 4 + r] = q;
        }
#pragma unroll
    for (int m = 1; m < 16; m <<= 1) {
#pragma unroll
        for (int i = 0; i < 16; ++i) {
            s1[i] += __shfl_xor(s1[i], m, 64);
            s2[i] += __shfl_xor(s2[i], m, 64);
        }
    }
    if (l15 == 0) {
#pragma unroll
        for (int a = 0; a < 4; ++a)
#pragma unroll
            for (int r = 0; r < 4; ++r) {
                int co = a * 16 + g * 4 + r;
                atomicAdd(&stats[co],      s1[a * 4 + r]);
                atomicAdd(&stats[64 + co], s2[a * 4 + r]);
            }
    }
}

__global__ __launch_bounds__(256) void finalize_kernel(float* __restrict__ out,
                                                       const float* __restrict__ stats,
                                                       const float* __restrict__ gamma,
                                                       const float* __restrict__ beta) {
    int i = blockIdx.x * 256 + threadIdx.x;
    if (i >= NVOX * 16) return;
    int cg = (i & 15) * 4;
    f32x4 v = *(f32x4*)(out + (size_t)i * 4);
    f32x4 r;
#pragma unroll
    for (int c = 0; c < 4; ++c) {
        int co = cg + c;
        float mean = stats[co] * (1.0f / NVOX);
        float var  = stats[64 + co] * (1.0f / NVOX) - mean * mean;
        float sc   = rsqrtf(var + 1e-5f) * gamma[co];
        float sh   = beta[co] - mean * sc;
        float yv   = v[c] * sc + sh;
        r[c] = yv > 0.f ? yv : expm1f(yv);
    }
    *(f32x4*)(out + (size_t)i * 4) = r;
}

extern "C" void kernel_launch(void* const* d_in, const int* in_sizes, int n_in,
                              void* d_out, int out_size, void* d_ws, size_t ws_size,
                              hipStream_t stream) {
    const float* feats  = (const float*)d_in[0];
    const int*   coords = (const int*)d_in[1];
    const float* Wt     = (const float*)d_in[2];
    // d_in[3] = bias: unused — cancels exactly under training-mode BN
    const float* gamma  = (const float*)d_in[4];
    const float* beta   = (const float*)d_in[5];
    float* out = (float*)d_out;
    char*  ws  = (char*)d_ws;

    unsigned short* wt  = (unsigned short*)(ws + WT_OFF);
    unsigned short* fb  = (unsigned short*)(ws + FB_OFF);
    int*   idx_map      = (int*)(ws + IDX_OFF);
    float* stats        = (float*)(ws + STATS_OFF);

    hipMemsetAsync(idx_map, 0xFF, (size_t)GRID_LIN * 4, stream);  // -1
    hipMemsetAsync(stats, 0, 128 * 4, stream);

    wconv_kernel<<<2000, 256, 0, stream>>>(Wt, wt);
    fconv_kernel<<<12501, 256, 0, stream>>>(feats, fb);
    scatter_kernel<<<782, 256, 0, stream>>>(coords, idx_map);
    conv_kernel<<<782, 256, 0, stream>>>(coords, fb, wt, idx_map, out, stats);
    finalize_kernel<<<12500, 256, 0, stream>>>(out, stats, gamma, beta);
}

// Round 2
// 1035.042 us; speedup vs baseline: 1.0113x; 1.0113x over previous
//
#include <hip/hip_runtime.h>
#include <hip/hip_bf16.h>

#define NVOX 200000
#define NK   125
#define GRID_LIN (128 * 128 * 128)

// workspace layout (bytes)
#define WT_OFF    0                      // 125*64*64*2 = 1,024,000
#define FB_OFF    (1u << 20)             // (N+1)*128   = 25,600,128
#define IDX_OFF   27262976u              // 2M * 4      = 8,388,608
#define STATS_OFF 35651584u              // 128 * 4

#define FCONV_N   (NVOX * 16 + 16)       // 3,200,016
#define WCONV_N   (NK * 4096)            // 512,000
#define PREP_N    (FCONV_N + WCONV_N + NVOX)   // 3,912,016

typedef short bf16x8 __attribute__((ext_vector_type(8)));
typedef float f32x4  __attribute__((ext_vector_type(4)));
typedef unsigned short u16x4 __attribute__((ext_vector_type(4)));

static __device__ __forceinline__ unsigned short f2bf(float f) {
    union { float f; unsigned int u; } v; v.f = f;
    unsigned int u = v.u;
    return (unsigned short)((u + 0x7FFFu + ((u >> 16) & 1u)) >> 16);   // RNE
}

// Fused prep: feats f32->bf16 (+zero row), W [125][ci][co] f32 -> [125][co][ci] bf16,
// coord scatter into idx_map. All jobs independent; idx_map pre-memset to -1.
__global__ __launch_bounds__(256) void prep_kernel(const float* __restrict__ Wt,
                                                   const float* __restrict__ feats,
                                                   const int* __restrict__ coords,
                                                   unsigned short* __restrict__ wt,
                                                   unsigned short* __restrict__ fb,
                                                   int* __restrict__ idx_map) {
    int i = blockIdx.x * 256 + threadIdx.x;
    if (i < NVOX * 16) {
        f32x4 f = *(const f32x4*)(feats + (size_t)i * 4);
        u16x4 u;
        u[0] = f2bf(f[0]); u[1] = f2bf(f[1]); u[2] = f2bf(f[2]); u[3] = f2bf(f[3]);
        *(u16x4*)(fb + (size_t)i * 4) = u;
    } else if (i < FCONV_N) {
        *(u16x4*)(fb + (size_t)i * 4) = (u16x4)0;
    } else if (i < FCONV_N + WCONV_N) {
        int j = i - FCONV_N;
        int k = j >> 12, r = j & 4095;
        int co = r >> 6, ci = r & 63;
        wt[j] = f2bf(Wt[(k << 12) + (ci << 6) + co]);
    } else if (i < PREP_N) {
        int p = i - (FCONV_N + WCONV_N);
        int z = coords[p * 3 + 0], y = coords[p * 3 + 1], x = coords[p * 3 + 2];
        idx_map[(z << 14) | (y << 7) | x] = p;
    }
}

// Implicit-GEMM conv, k-split across 4 waves.
// Block = 64 voxels; wave w handles k in [w*125/4, (w+1)*125/4).
// Phase 1: bulk-gather all 125*64 neighbor row-indices into LDS (independent loads).
// Phase 2: per k: jt from LDS (no shuffle), A from L2-resident wt, B gathered rows,
//          32 MFMA. No per-iter dependent-gather chain.
// Phase 3: LDS tree-reduce the 4 partial 64x64 accumulators; wave 0 stores + BN stats.
__global__ __launch_bounds__(256, 4) void conv_kernel(
    const int* __restrict__ coords, const unsigned short* __restrict__ fb,
    const unsigned short* __restrict__ wt, const int* __restrict__ idx_map,
    float* __restrict__ out, float* __restrict__ stats) {
    __shared__ int lds_u[8192];      // 32 KB: phase1/2 = nbr[125][64]; phase3 = f32 reduce buf
    __shared__ int lds_zyx[192];

    const int tid  = threadIdx.x;
    const int vbase = blockIdx.x * 64;

    if (tid < 192) lds_zyx[tid] = coords[vbase * 3 + tid];
    __syncthreads();

    // Phase 1: neighbor row-index table (sentinel NVOX -> zero row)
    for (int e = tid; e < NK * 64; e += 256) {
        int k = e >> 6, vl = e & 63;
        int z = lds_zyx[vl * 3 + 0], y = lds_zyx[vl * 3 + 1], x = lds_zyx[vl * 3 + 2];
        int dz = k / 25 - 2, rem = k % 25;
        int dy = rem / 5 - 2, dx = rem % 5 - 2;
        int nz = z + dz, ny = y + dy, nx = x + dx;
        int j = NVOX;
        if (((unsigned)nz < 128u) & ((unsigned)ny < 128u) & ((unsigned)nx < 128u)) {
            int t = idx_map[(nz << 14) | (ny << 7) | nx];
            if (t >= 0) j = t;
        }
        lds_u[e] = j;
    }
    __syncthreads();

    const int wave = tid >> 6;
    const int lane = tid & 63;
    const int g    = lane >> 4;
    const int l15  = lane & 15;
    const int kbeg = (wave * NK) >> 2;
    const int kend = ((wave + 1) * NK) >> 2;

    f32x4 acc[4][4];
#pragma unroll
    for (int a = 0; a < 4; ++a)
#pragma unroll
        for (int b = 0; b < 4; ++b) acc[a][b] = (f32x4)0.0f;

    const char* fbp = (const char*)fb;
    for (int k = kbeg; k < kend; ++k) {
        const char* wp = (const char*)wt + (size_t)k * 8192;
        int jt[4];
#pragma unroll
        for (int t = 0; t < 4; ++t) jt[t] = lds_u[(k << 6) + t * 16 + l15];

#pragma unroll
        for (int s = 0; s < 2; ++s) {
            bf16x8 afrag[4], bfrag[4];
#pragma unroll
            for (int a = 0; a < 4; ++a)
                afrag[a] = *(const bf16x8*)(wp + (((a * 16 + l15) << 7) + (g << 4) + (s << 6)));
#pragma unroll
            for (int t = 0; t < 4; ++t)
                bfrag[t] = *(const bf16x8*)(fbp + (((size_t)(unsigned)jt[t] << 7) + (g << 4) + (s << 6)));
#pragma unroll
            for (int a = 0; a < 4; ++a)
#pragma unroll
                for (int b = 0; b < 4; ++b)
                    acc[a][b] = __builtin_amdgcn_mfma_f32_16x16x32_bf16(afrag[a], bfrag[b], acc[a][b], 0, 0, 0);
        }
    }

    // Phase 3: cross-wave reduction of the 4 k-partials
    __syncthreads();                      // nbr table dead; reuse lds_u as float buf
    f32x4* lf = (f32x4*)lds_u;            // 2048 f32x4 slots = 32 KB
    if (wave >= 2) {
#pragma unroll
        for (int a = 0; a < 4; ++a)
#pragma unroll
            for (int b = 0; b < 4; ++b)
                lf[(wave - 2) * 1024 + lane * 16 + a * 4 + b] = acc[a][b];
    }
    __syncthreads();
    if (wave < 2) {
#pragma unroll
        for (int a = 0; a < 4; ++a)
#pragma unroll
            for (int b = 0; b < 4; ++b)
                acc[a][b] += lf[wave * 1024 + lane * 16 + a * 4 + b];
    }
    __syncthreads();
    if (wave == 1) {
#pragma unroll
        for (int a = 0; a < 4; ++a)
#pragma unroll
            for (int b = 0; b < 4; ++b)
                lf[lane * 16 + a * 4 + b] = acc[a][b];
    }
    __syncthreads();
    if (wave == 0) {
#pragma unroll
        for (int a = 0; a < 4; ++a)
#pragma unroll
            for (int b = 0; b < 4; ++b)
                acc[a][b] += lf[lane * 16 + a * 4 + b];

        // store conv result (pre-BN; bias cancels under train-mode BN)
#pragma unroll
        for (int b = 0; b < 4; ++b) {
            int v = vbase + b * 16 + l15;
#pragma unroll
            for (int a = 0; a < 4; ++a)
                *(f32x4*)(out + (size_t)v * 64 + a * 16 + g * 4) = acc[a][b];
        }

        // BN batch-stat partials over this block's 64 voxels
        float s1[16], s2[16];
#pragma unroll
        for (int a = 0; a < 4; ++a)
#pragma unroll
            for (int r = 0; r < 4; ++r) {
                float s = 0.f, q = 0.f;
#pragma unroll
                for (int b = 0; b < 4; ++b) { float xv = acc[a][b][r]; s += xv; q += xv * xv; }
                s1[a * 4 + r] = s; s2[a * 4 + r] = q;
            }
#pragma unroll
        for (int m = 1; m < 16; m <<= 1) {
#pragma unroll
            for (int i = 0; i < 16; ++i) {
                s1[i] += __shfl_xor(s1[i], m, 64);
                s2[i] += __shfl_xor(s2[i], m, 64);
            }
        }
        if (l15 == 0) {
#pragma unroll
            for (int a = 0; a < 4; ++a)
#pragma unroll
                for (int r = 0; r < 4; ++r) {
                    int co = a * 16 + g * 4 + r;
                    atomicAdd(&stats[co],      s1[a * 4 + r]);
                    atomicAdd(&stats[64 + co], s2[a * 4 + r]);
                }
        }
    }
}

__global__ __launch_bounds__(256) void finalize_kernel(float* __restrict__ out,
                                                       const float* __restrict__ stats,
                                                       const float* __restrict__ gamma,
                                                       const float* __restrict__ beta) {
    int i = blockIdx.x * 256 + threadIdx.x;
    if (i >= NVOX * 16) return;
    int cg = (i & 15) * 4;
    f32x4 v = *(f32x4*)(out + (size_t)i * 4);
    f32x4 r;
#pragma unroll
    for (int c = 0; c < 4; ++c) {
        int co = cg + c;
        float mean = stats[co] * (1.0f / NVOX);
        float var  = stats[64 + co] * (1.0f / NVOX) - mean * mean;
        float sc   = rsqrtf(var + 1e-5f) * gamma[co];
        float sh   = beta[co] - mean * sc;
        float yv   = v[c] * sc + sh;
        r[c] = yv > 0.f ? yv : expm1f(yv);
    }
    *(f32x4*)(out + (size_t)i * 4) = r;
}

extern "C" void kernel_launch(void* const* d_in, const int* in_sizes, int n_in,
                              void* d_out, int out_size, void* d_ws, size_t ws_size,
                              hipStream_t stream) {
    const float* feats  = (const float*)d_in[0];
    const int*   coords = (const int*)d_in[1];
    const float* Wt     = (const float*)d_in[2];
    // d_in[3] = bias: unused — cancels exactly under training-mode BN
    const float* gamma  = (const float*)d_in[4];
    const float* beta   = (const float*)d_in[5];
    float* out = (float*)d_out;
    char*  ws  = (char*)d_ws;

    unsigned short* wt  = (unsigned short*)(ws + WT_OFF);
    unsigned short* fb  = (unsigned short*)(ws + FB_OFF);
    int*   idx_map      = (int*)(ws + IDX_OFF);
    float* stats        = (float*)(ws + STATS_OFF);

    hipMemsetAsync(idx_map, 0xFF, (size_t)GRID_LIN * 4, stream);  // -1
    hipMemsetAsync(stats, 0, 128 * 4, stream);

    prep_kernel<<<(PREP_N + 255) / 256, 256, 0, stream>>>(Wt, feats, coords, wt, fb, idx_map);
    conv_kernel<<<NVOX / 64, 256, 0, stream>>>(coords, fb, wt, idx_map, out, stats);
    finalize_kernel<<<12500, 256, 0, stream>>>(out, stats, gamma, beta);
}

// Round 3
// 890.355 us; speedup vs baseline: 1.1756x; 1.1625x over previous
//
#include <hip/hip_runtime.h>
#include <hip/hip_bf16.h>

#define NVOX 200000
#define NK   125
#define KCH  25
#define GRID_LIN (128 * 128 * 128)

// workspace layout (bytes)
#define WT_OFF    0                      // 125*64*64*2 = 1,024,000
#define FB_OFF    (1u << 20)             // (N+1)*128   = 25,600,128
#define IDX_OFF   27262976u              // 2M * 4      = 8,388,608
#define STATS_OFF 35651584u              // 128 * 4

#define FCONV_N   (NVOX * 16 + 16)       // 3,200,016
#define WCONV_N   (NK * 4096)            // 512,000
#define PREP_N    (FCONV_N + WCONV_N + NVOX)

typedef short bf16x8 __attribute__((ext_vector_type(8)));
typedef float f32x4  __attribute__((ext_vector_type(4)));
typedef unsigned short u16x4 __attribute__((ext_vector_type(4)));
typedef unsigned int uint_as1 __attribute__((address_space(1)));
typedef unsigned int uint_as3 __attribute__((address_space(3)));

static __device__ __forceinline__ unsigned short f2bf(float f) {
    union { float f; unsigned int u; } v; v.f = f;
    unsigned int u = v.u;
    return (unsigned short)((u + 0x7FFFu + ((u >> 16) & 1u)) >> 16);   // RNE
}

// Fused prep: feats f32->bf16 (+zero row), W [125][ci][co] -> [125][co][ci] bf16,
// coord scatter into idx_map (pre-memset to -1).
__global__ __launch_bounds__(256) void prep_kernel(const float* __restrict__ Wt,
                                                   const float* __restrict__ feats,
                                                   const int* __restrict__ coords,
                                                   unsigned short* __restrict__ wt,
                                                   unsigned short* __restrict__ fb,
                                                   int* __restrict__ idx_map) {
    int i = blockIdx.x * 256 + threadIdx.x;
    if (i < NVOX * 16) {
        f32x4 f = *(const f32x4*)(feats + (size_t)i * 4);
        u16x4 u;
        u[0] = f2bf(f[0]); u[1] = f2bf(f[1]); u[2] = f2bf(f[2]); u[3] = f2bf(f[3]);
        *(u16x4*)(fb + (size_t)i * 4) = u;
    } else if (i < FCONV_N) {
        *(u16x4*)(fb + (size_t)i * 4) = (u16x4)0;
    } else if (i < FCONV_N + WCONV_N) {
        int j = i - FCONV_N;
        int k = j >> 12, r = j & 4095;
        int co = r >> 6, ci = r & 63;
        wt[j] = f2bf(Wt[(k << 12) + (ci << 6) + co]);
    } else if (i < PREP_N) {
        int p = i - (FCONV_N + WCONV_N);
        int z = coords[p * 3 + 0], y = coords[p * 3 + 1], x = coords[p * 3 + 2];
        idx_map[(z << 14) | (y << 7) | x] = p;
    }
}

// stage W_k (8KB) into LDS: 256 threads x 2 x 16B, wave-contiguous (base + lane*16)
static __device__ __forceinline__ void stage_w(const unsigned short* wt, int k,
                                               unsigned short* dst, int tid) {
    const unsigned short* src = wt + ((size_t)k << 12) + tid * 8;
    __builtin_amdgcn_global_load_lds((const uint_as1*)(const void*)src,
                                     (uint_as3*)(void*)(dst + tid * 8), 16, 0, 0);
    __builtin_amdgcn_global_load_lds((const uint_as1*)(const void*)(src + 2048),
                                     (uint_as3*)(void*)(dst + tid * 8 + 2048), 16, 0, 0);
}

// Block = 256 voxels; wave w owns voxels [vbase+w*64, +64) for ALL 125 k (no reduce).
// Per k: W_k from double-buffered LDS (staged once per block), B rows gathered from
// global (invalid -> zero row), 32 MFMA per wave. Neighbor table chunked in LDS.
__global__ __launch_bounds__(256, 2) void conv_kernel(
    const int* __restrict__ coords, const unsigned short* __restrict__ fb,
    const unsigned short* __restrict__ wt, const int* __restrict__ idx_map,
    float* __restrict__ out, float* __restrict__ stats) {
    __shared__ int lds_nbr[KCH * 256];          // 25.6 KB, transposed [kk][w][l15][t]
    __shared__ unsigned short lds_w[2][4096];   // 2 x 8 KB double buffer

    const int tid  = threadIdx.x;
    const int wave = tid >> 6;
    const int lane = tid & 63;
    const int g    = lane >> 4;
    const int l15  = lane & 15;
    const int vbase = blockIdx.x * 256;
    const int vox   = vbase + tid;
    const bool live = vox < NVOX;

    int z = 0, y = 0, x = 0;
    if (live) { z = coords[vox * 3 + 0]; y = coords[vox * 3 + 1]; x = coords[vox * 3 + 2]; }
    // transposed slot so compute reads jt[0..3] as one b128
    const int slot = (tid & ~63) | ((tid & 15) << 2) | ((tid >> 4) & 3);

    f32x4 acc[4][4];
#pragma unroll
    for (int a = 0; a < 4; ++a)
#pragma unroll
        for (int b = 0; b < 4; ++b) acc[a][b] = (f32x4)0.0f;

    const char* fbp = (const char*)fb;
    int buf = 0;
    stage_w(wt, 0, &lds_w[0][0], tid);

    for (int c = 0; c < 5; ++c) {
        if (c) __syncthreads();                 // previous chunk's nbr readers done
        // gather neighbor rows for k in [c*25, c*25+25); dz == c-2
        const int dz = c - 2, nz = z + dz;
        const bool zok = live && ((unsigned)nz < 128u);
#pragma unroll 5
        for (int kk = 0; kk < KCH; ++kk) {
            int dy = kk / 5 - 2, dx = kk % 5 - 2;
            int ny = y + dy, nx = x + dx;
            int j = NVOX;
            if (zok && ((unsigned)ny < 128u) & ((unsigned)nx < 128u)) {
                int t = idx_map[(nz << 14) | (ny << 7) | nx];
                if (t >= 0) j = t;
            }
            lds_nbr[kk * 256 + slot] = j;
        }
        __syncthreads();                        // nbr + pending W stage visible

        for (int kk = 0; kk < KCH; ++kk) {
            int k = c * KCH + kk;
            if (k + 1 < NK) stage_w(wt, k + 1, &lds_w[buf ^ 1][0], tid);

            int4 jt4 = *(const int4*)&lds_nbr[kk * 256 + wave * 64 + l15 * 4];
            const int jt[4] = {jt4.x, jt4.y, jt4.z, jt4.w};
            const char* wb = (const char*)&lds_w[buf][0];
#pragma unroll
            for (int s = 0; s < 2; ++s) {
                bf16x8 bfrag[4];
#pragma unroll
                for (int t = 0; t < 4; ++t)
                    bfrag[t] = *(const bf16x8*)(fbp + (((size_t)(unsigned)jt[t] << 7) + (g << 4) + (s << 6)));
#pragma unroll
                for (int a = 0; a < 4; ++a) {
                    bf16x8 afrag = *(const bf16x8*)(wb + (((a * 16 + l15) << 7) + (g << 4) + (s << 6)));
#pragma unroll
                    for (int b = 0; b < 4; ++b)
                        acc[a][b] = __builtin_amdgcn_mfma_f32_16x16x32_bf16(afrag, bfrag[b], acc[a][b], 0, 0, 0);
                }
            }
            buf ^= 1;
            if (kk < KCH - 1) __syncthreads();  // make stage(k+1) visible; hides its latency behind compute(k)
        }
    }

    // epilogue: store pre-BN conv result (bias cancels under train-mode BN)
#pragma unroll
    for (int b = 0; b < 4; ++b) {
        int v = vbase + wave * 64 + b * 16 + l15;
        if (v < NVOX) {
#pragma unroll
            for (int a = 0; a < 4; ++a)
                *(f32x4*)(out + (size_t)v * 64 + a * 16 + g * 4) = acc[a][b];
        }
    }

    // BN batch-stat partials over this wave's 64 voxels (dead voxels contribute 0)
    float s1[16], s2[16];
#pragma unroll
    for (int a = 0; a < 4; ++a)
#pragma unroll
        for (int r = 0; r < 4; ++r) {
            float s = 0.f, q = 0.f;
#pragma unroll
            for (int b = 0; b < 4; ++b) { float xv = acc[a][b][r]; s += xv; q += xv * xv; }
            s1[a * 4 + r] = s; s2[a * 4 + r] = q;
        }
#pragma unroll
    for (int m = 1; m < 16; m <<= 1) {
#pragma unroll
        for (int i = 0; i < 16; ++i) {
            s1[i] += __shfl_xor(s1[i], m, 64);
            s2[i] += __shfl_xor(s2[i], m, 64);
        }
    }
    if (l15 == 0) {
#pragma unroll
        for (int a = 0; a < 4; ++a)
#pragma unroll
            for (int r = 0; r < 4; ++r) {
                int co = a * 16 + g * 4 + r;
                atomicAdd(&stats[co],      s1[a * 4 + r]);
                atomicAdd(&stats[64 + co], s2[a * 4 + r]);
            }
    }
}

__global__ __launch_bounds__(256) void finalize_kernel(float* __restrict__ out,
                                                       const float* __restrict__ stats,
                                                       const float* __restrict__ gamma,
                                                       const float* __restrict__ beta) {
    int i = blockIdx.x * 256 + threadIdx.x;
    if (i >= NVOX * 16) return;
    int cg = (i & 15) * 4;
    f32x4 v = *(f32x4*)(out + (size_t)i * 4);
    f32x4 r;
#pragma unroll
    for (int c = 0; c < 4; ++c) {
        int co = cg + c;
        float mean = stats[co] * (1.0f / NVOX);
        float var  = stats[64 + co] * (1.0f / NVOX) - mean * mean;
        float sc   = rsqrtf(var + 1e-5f) * gamma[co];
        float sh   = beta[co] - mean * sc;
        float yv   = v[c] * sc + sh;
        r[c] = yv > 0.f ? yv : expm1f(yv);
    }
    *(f32x4*)(out + (size_t)i * 4) = r;
}

extern "C" void kernel_launch(void* const* d_in, const int* in_sizes, int n_in,
                              void* d_out, int out_size, void* d_ws, size_t ws_size,
                              hipStream_t stream) {
    const float* feats  = (const float*)d_in[0];
    const int*   coords = (const int*)d_in[1];
    const float* Wt     = (const float*)d_in[2];
    // d_in[3] = bias: unused — cancels exactly under training-mode BN
    const float* gamma  = (const float*)d_in[4];
    const float* beta   = (const float*)d_in[5];
    float* out = (float*)d_out;
    char*  ws  = (char*)d_ws;

    unsigned short* wt  = (unsigned short*)(ws + WT_OFF);
    unsigned short* fb  = (unsigned short*)(ws + FB_OFF);
    int*   idx_map      = (int*)(ws + IDX_OFF);
    float* stats        = (float*)(ws + STATS_OFF);

    hipMemsetAsync(idx_map, 0xFF, (size_t)GRID_LIN * 4, stream);  // -1
    hipMemsetAsync(stats, 0, 128 * 4, stream);

    prep_kernel<<<(PREP_N + 255) / 256, 256, 0, stream>>>(Wt, feats, coords, wt, fb, idx_map);
    conv_kernel<<<(NVOX + 255) / 256, 256, 0, stream>>>(coords, fb, wt, idx_map, out, stats);
    finalize_kernel<<<12500, 256, 0, stream>>>(out, stats, gamma, beta);
}

// Round 4
// 774.971 us; speedup vs baseline: 1.3507x; 1.1489x over previous
//
#include <hip/hip_runtime.h>
#include <hip/hip_bf16.h>

#define NVOX 200000
#define NK   125
#define KCH  25
#define GRID_LIN (128 * 128 * 128)

// workspace layout (bytes)
#define WT_OFF    0u                    // 125*64*64*2      = 1,024,000
#define STATS_OFF 1024000u              // 128*4            = 512
#define PFX_OFF   1024512u              // 2048*4           = 8,192
#define OLD_OFF   1032704u              // 200,000*4        = 800,000
#define FB_OFF    1832704u              // (N+1)*128        = 25,600,128  (128B aligned)
#define IDX_OFF   27432832u             // 2M*4             = 8,388,608   -> ends 35,821,440

#define F16N   (NVOX * 16)              // 3,200,000
#define WCONV_N (NK * 4096)             // 512,000
#define PREP_N (F16N + 16 + WCONV_N)    // 3,712,016

typedef short bf16x8 __attribute__((ext_vector_type(8)));
typedef float f32x4  __attribute__((ext_vector_type(4)));
typedef unsigned short u16x4 __attribute__((ext_vector_type(4)));
typedef unsigned int uint_as1 __attribute__((address_space(1)));
typedef unsigned int uint_as3 __attribute__((address_space(3)));

static __device__ __forceinline__ unsigned short f2bf(float f) {
    union { float f; unsigned int u; } v; v.f = f;
    unsigned int u = v.u;
    return (unsigned short)((u + 0x7FFFu + ((u >> 16) & 1u)) >> 16);   // RNE
}

// K1: scatter original voxel id into idx_map (pre-memset to -1)
__global__ __launch_bounds__(256) void scatter_kernel(const int* __restrict__ coords,
                                                      int* __restrict__ idx_map) {
    int p = blockIdx.x * 256 + threadIdx.x;
    if (p < NVOX) {
        int z = coords[p * 3 + 0], y = coords[p * 3 + 1], x = coords[p * 3 + 2];
        idx_map[(z << 14) | (y << 7) | x] = p;
    }
}

// K2: per-1024-cell occupancy count
__global__ __launch_bounds__(1024) void count_kernel(const int* __restrict__ idx_map,
                                                     int* __restrict__ pfx) {
    __shared__ int wsum[16];
    int i = blockIdx.x * 1024 + threadIdx.x;
    int bit = idx_map[i] >= 0 ? 1 : 0;
    unsigned long long m = __ballot(bit);
    int lane = threadIdx.x & 63, wave = threadIdx.x >> 6;
    if (lane == 0) wsum[wave] = __popcll(m);
    __syncthreads();
    if (threadIdx.x == 0) {
        int s = 0;
#pragma unroll
        for (int w = 0; w < 16; ++w) s += wsum[w];
        pfx[blockIdx.x] = s;
    }
}

// K3: exclusive scan of 2048 block counts, single block (double-buffered Hillis-Steele)
__global__ __launch_bounds__(1024) void scan_kernel(int* __restrict__ pfx) {
    __shared__ int A[2048], B[2048];
    int t = threadIdx.x;
    A[t] = pfx[t]; A[t + 1024] = pfx[t + 1024];
    __syncthreads();
    int* src = A; int* dst = B;
    for (int off = 1; off < 2048; off <<= 1) {
        dst[t]        = src[t]        + (t >= off ? src[t - off] : 0);
        dst[t + 1024] = src[t + 1024] + src[t + 1024 - off];
        __syncthreads();
        int* tmp = src; src = dst; dst = tmp;
    }
    // src holds inclusive scan; write exclusive
    pfx[t]        = t ? src[t - 1] : 0;
    pfx[t + 1024] = src[t + 1023];
}

// K4: relabel cells in spatial order; idx_map[cell] <- new id; oldof[new] = old id
__global__ __launch_bounds__(1024) void relabel_kernel(const int* __restrict__ pfx,
                                                       int* __restrict__ idx_map,
                                                       int* __restrict__ oldof) {
    __shared__ int wsum[16];
    int i = blockIdx.x * 1024 + threadIdx.x;
    int old = idx_map[i];
    int bit = old >= 0 ? 1 : 0;
    unsigned long long m = __ballot(bit);
    int lane = threadIdx.x & 63, wave = threadIdx.x >> 6;
    int intra = __popcll(m & ((1ull << lane) - 1ull));
    if (lane == 0) wsum[wave] = __popcll(m);
    __syncthreads();
    int woff = 0;
    for (int w = 0; w < wave; ++w) woff += wsum[w];
    if (bit) {
        int nid = pfx[blockIdx.x] + woff + intra;
        idx_map[i] = nid;
        oldof[nid] = old;
    }
}

// K5: fused prep — feats permuted f32->bf16 (+zero row), W [125][ci][co] -> [125][co][ci] bf16
__global__ __launch_bounds__(256) void prep_kernel(const float* __restrict__ Wt,
                                                   const float* __restrict__ feats,
                                                   const int* __restrict__ oldof,
                                                   unsigned short* __restrict__ wt,
                                                   unsigned short* __restrict__ fb) {
    int i = blockIdx.x * 256 + threadIdx.x;
    if (i < F16N) {
        int p = i >> 4, c = i & 15;
        int old = oldof[p];
        f32x4 f = *(const f32x4*)(feats + (size_t)old * 64 + c * 4);
        u16x4 u;
        u[0] = f2bf(f[0]); u[1] = f2bf(f[1]); u[2] = f2bf(f[2]); u[3] = f2bf(f[3]);
        *(u16x4*)(fb + (size_t)i * 4) = u;
    } else if (i < F16N + 16) {
        *(u16x4*)(fb + (size_t)i * 4) = (u16x4)0;
    } else if (i < PREP_N) {
        int j = i - (F16N + 16);
        int k = j >> 12, r = j & 4095;
        int co = r >> 6, ci = r & 63;
        wt[j] = f2bf(Wt[(k << 12) + (ci << 6) + co]);
    }
}

// stage W_k (8KB) into LDS: 256 threads x 2 x 16B, wave-contiguous
static __device__ __forceinline__ void stage_w(const unsigned short* wt, int k,
                                               unsigned short* dst, int tid) {
    const unsigned short* src = wt + ((size_t)k << 12) + tid * 8;
    __builtin_amdgcn_global_load_lds((const uint_as1*)(const void*)src,
                                     (uint_as3*)(void*)(dst + tid * 8), 16, 0, 0);
    __builtin_amdgcn_global_load_lds((const uint_as1*)(const void*)(src + 2048),
                                     (uint_as3*)(void*)(dst + tid * 8 + 2048), 16, 0, 0);
}

// Conv over spatially-relabeled voxels. Block = 256 consecutive (spatial) voxels.
// XCD swizzle: blocks b with b&7==x own a contiguous label slab on XCD x, so each
// XCD's L2 holds its slab's feats (~0.8 MB) + idx_map window (~0.3 MB).
__global__ __launch_bounds__(256, 2) void conv_kernel(
    const int* __restrict__ coords, const unsigned short* __restrict__ fb,
    const unsigned short* __restrict__ wt, const int* __restrict__ idx_map,
    const int* __restrict__ oldof,
    float* __restrict__ out, float* __restrict__ stats) {
    __shared__ int lds_nbr[KCH * 256];          // 25.6 KB, transposed [kk][w][l15][t]
    __shared__ unsigned short lds_w[2][4096];   // 2 x 8 KB double buffer

    const int vblk = (blockIdx.x & 7) * 98 + (blockIdx.x >> 3);
    const int vbase = vblk * 256;
    if (vbase >= NVOX) return;

    const int tid  = threadIdx.x;
    const int wave = tid >> 6;
    const int lane = tid & 63;
    const int g    = lane >> 4;
    const int l15  = lane & 15;
    const int vox  = vbase + tid;
    const bool live = vox < NVOX;

    int z = 0, y = 0, x = 0;
    if (live) {
        int old = oldof[vox];
        z = coords[old * 3 + 0]; y = coords[old * 3 + 1]; x = coords[old * 3 + 2];
    }
    const int slot = (tid & ~63) | ((tid & 15) << 2) | ((tid >> 4) & 3);

    f32x4 acc[4][4];
#pragma unroll
    for (int a = 0; a < 4; ++a)
#pragma unroll
        for (int b = 0; b < 4; ++b) acc[a][b] = (f32x4)0.0f;

    const char* fbp = (const char*)fb;
    int buf = 0;
    stage_w(wt, 0, &lds_w[0][0], tid);

    for (int c = 0; c < 5; ++c) {
        if (c) __syncthreads();
        const int dz = c - 2, nz = z + dz;
        const bool zok = live && ((unsigned)nz < 128u);
#pragma unroll 5
        for (int kk = 0; kk < KCH; ++kk) {
            int dy = kk / 5 - 2, dx = kk % 5 - 2;
            int ny = y + dy, nx = x + dx;
            int j = NVOX;
            if (zok && ((unsigned)ny < 128u) & ((unsigned)nx < 128u)) {
                int t = idx_map[(nz << 14) | (ny << 7) | nx];
                if (t >= 0) j = t;
            }
            lds_nbr[kk * 256 + slot] = j;
        }
        __syncthreads();

        for (int kk = 0; kk < KCH; ++kk) {
            int k = c * KCH + kk;
            if (k + 1 < NK) stage_w(wt, k + 1, &lds_w[buf ^ 1][0], tid);

            int4 jt4 = *(const int4*)&lds_nbr[kk * 256 + wave * 64 + l15 * 4];
            const int jt[4] = {jt4.x, jt4.y, jt4.z, jt4.w};
            const char* wb = (const char*)&lds_w[buf][0];
#pragma unroll
            for (int s = 0; s < 2; ++s) {
                bf16x8 bfrag[4];
#pragma unroll
                for (int t = 0; t < 4; ++t)
                    bfrag[t] = *(const bf16x8*)(fbp + (((size_t)(unsigned)jt[t] << 7) + (g << 4) + (s << 6)));
#pragma unroll
                for (int a = 0; a < 4; ++a) {
                    bf16x8 afrag = *(const bf16x8*)(wb + (((a * 16 + l15) << 7) + (g << 4) + (s << 6)));
#pragma unroll
                    for (int b = 0; b < 4; ++b)
                        acc[a][b] = __builtin_amdgcn_mfma_f32_16x16x32_bf16(afrag, bfrag[b], acc[a][b], 0, 0, 0);
                }
            }
            buf ^= 1;
            if (kk < KCH - 1) __syncthreads();
        }
    }

    // epilogue: scatter rows back to ORIGINAL voxel order (bias cancels under BN)
#pragma unroll
    for (int b = 0; b < 4; ++b) {
        int v = vbase + wave * 64 + b * 16 + l15;
        if (v < NVOX) {
            int o = oldof[v];
#pragma unroll
            for (int a = 0; a < 4; ++a)
                *(f32x4*)(out + (size_t)o * 64 + a * 16 + g * 4) = acc[a][b];
        }
    }

    // BN batch-stat partials over this wave's 64 voxels
    float s1[16], s2[16];
#pragma unroll
    for (int a = 0; a < 4; ++a)
#pragma unroll
        for (int r = 0; r < 4; ++r) {
            float s = 0.f, q = 0.f;
#pragma unroll
            for (int b = 0; b < 4; ++b) { float xv = acc[a][b][r]; s += xv; q += xv * xv; }
            s1[a * 4 + r] = s; s2[a * 4 + r] = q;
        }
#pragma unroll
    for (int m = 1; m < 16; m <<= 1) {
#pragma unroll
        for (int i = 0; i < 16; ++i) {
            s1[i] += __shfl_xor(s1[i], m, 64);
            s2[i] += __shfl_xor(s2[i], m, 64);
        }
    }
    if (l15 == 0) {
#pragma unroll
        for (int a = 0; a < 4; ++a)
#pragma unroll
            for (int r = 0; r < 4; ++r) {
                int co = a * 16 + g * 4 + r;
                atomicAdd(&stats[co],      s1[a * 4 + r]);
                atomicAdd(&stats[64 + co], s2[a * 4 + r]);
            }
    }
}

__global__ __launch_bounds__(256) void finalize_kernel(float* __restrict__ out,
                                                       const float* __restrict__ stats,
                                                       const float* __restrict__ gamma,
                                                       const float* __restrict__ beta) {
    int i = blockIdx.x * 256 + threadIdx.x;
    if (i >= NVOX * 16) return;
    int cg = (i & 15) * 4;
    f32x4 v = *(f32x4*)(out + (size_t)i * 4);
    f32x4 r;
#pragma unroll
    for (int c = 0; c < 4; ++c) {
        int co = cg + c;
        float mean = stats[co] * (1.0f / NVOX);
        float var  = stats[64 + co] * (1.0f / NVOX) - mean * mean;
        float sc   = rsqrtf(var + 1e-5f) * gamma[co];
        float sh   = beta[co] - mean * sc;
        float yv   = v[c] * sc + sh;
        r[c] = yv > 0.f ? yv : expm1f(yv);
    }
    *(f32x4*)(out + (size_t)i * 4) = r;
}

extern "C" void kernel_launch(void* const* d_in, const int* in_sizes, int n_in,
                              void* d_out, int out_size, void* d_ws, size_t ws_size,
                              hipStream_t stream) {
    const float* feats  = (const float*)d_in[0];
    const int*   coords = (const int*)d_in[1];
    const float* Wt     = (const float*)d_in[2];
    // d_in[3] = bias: unused — cancels exactly under training-mode BN
    const float* gamma  = (const float*)d_in[4];
    const float* beta   = (const float*)d_in[5];
    float* out = (float*)d_out;
    char*  ws  = (char*)d_ws;

    unsigned short* wt  = (unsigned short*)(ws + WT_OFF);
    float* stats        = (float*)(ws + STATS_OFF);
    int*   pfx          = (int*)(ws + PFX_OFF);
    int*   oldof        = (int*)(ws + OLD_OFF);
    unsigned short* fb  = (unsigned short*)(ws + FB_OFF);
    int*   idx_map      = (int*)(ws + IDX_OFF);

    hipMemsetAsync(idx_map, 0xFF, (size_t)GRID_LIN * 4, stream);  // -1
    hipMemsetAsync(stats, 0, 128 * 4, stream);

    scatter_kernel<<<(NVOX + 255) / 256, 256, 0, stream>>>(coords, idx_map);
    count_kernel<<<GRID_LIN / 1024, 1024, 0, stream>>>(idx_map, pfx);
    scan_kernel<<<1, 1024, 0, stream>>>(pfx);
    relabel_kernel<<<GRID_LIN / 1024, 1024, 0, stream>>>(pfx, idx_map, oldof);
    prep_kernel<<<(PREP_N + 255) / 256, 256, 0, stream>>>(Wt, feats, oldof, wt, fb);
    conv_kernel<<<784, 256, 0, stream>>>(coords, fb, wt, idx_map, oldof, out, stats);
    finalize_kernel<<<12500, 256, 0, stream>>>(out, stats, gamma, beta);
}

// Round 5
// 755.681 us; speedup vs baseline: 1.3852x; 1.0255x over previous
//
#include <hip/hip_runtime.h>
#include <hip/hip_bf16.h>

#define NVOX 200000
#define NK   125
#define KG   5                          // k-group size (one (dz,dy) row)
#define GRID_LIN (128 * 128 * 128)

// workspace layout (bytes)
#define WT_OFF    0u                    // 125*64*64*2      = 1,024,000
#define STATS_OFF 1024000u              // 128*4            = 512
#define PFX_OFF   1024512u              // 2048*4           = 8,192
#define OLD_OFF   1032704u              // 200,000*4        = 800,000
#define FB_OFF    1832704u              // (N+1)*128        = 25,600,128  (128B aligned)
#define IDX_OFF   27432832u             // 2M*4             = 8,388,608   -> ends 35,821,440

#define F16N   (NVOX * 16)              // 3,200,000
#define WCONV_N (NK * 4096)             // 512,000
#define PREP_N (F16N + 16 + WCONV_N)    // 3,712,016

typedef short bf16x8 __attribute__((ext_vector_type(8)));
typedef float f32x4  __attribute__((ext_vector_type(4)));
typedef unsigned short u16x4 __attribute__((ext_vector_type(4)));
typedef unsigned int uint_as1 __attribute__((address_space(1)));
typedef unsigned int uint_as3 __attribute__((address_space(3)));

static __device__ __forceinline__ unsigned short f2bf(float f) {
    union { float f; unsigned int u; } v; v.f = f;
    unsigned int u = v.u;
    return (unsigned short)((u + 0x7FFFu + ((u >> 16) & 1u)) >> 16);   // RNE
}

// K1: scatter original voxel id into idx_map (pre-memset to -1)
__global__ __launch_bounds__(256) void scatter_kernel(const int* __restrict__ coords,
                                                      int* __restrict__ idx_map) {
    int p = blockIdx.x * 256 + threadIdx.x;
    if (p < NVOX) {
        int z = coords[p * 3 + 0], y = coords[p * 3 + 1], x = coords[p * 3 + 2];
        idx_map[(z << 14) | (y << 7) | x] = p;
    }
}

// K2: per-1024-cell occupancy count
__global__ __launch_bounds__(1024) void count_kernel(const int* __restrict__ idx_map,
                                                     int* __restrict__ pfx) {
    __shared__ int wsum[16];
    int i = blockIdx.x * 1024 + threadIdx.x;
    int bit = idx_map[i] >= 0 ? 1 : 0;
    unsigned long long m = __ballot(bit);
    int lane = threadIdx.x & 63, wave = threadIdx.x >> 6;
    if (lane == 0) wsum[wave] = __popcll(m);
    __syncthreads();
    if (threadIdx.x == 0) {
        int s = 0;
#pragma unroll
        for (int w = 0; w < 16; ++w) s += wsum[w];
        pfx[blockIdx.x] = s;
    }
}

// K3: exclusive scan of 2048 block counts, single block
__global__ __launch_bounds__(1024) void scan_kernel(int* __restrict__ pfx) {
    __shared__ int A[2048], B[2048];
    int t = threadIdx.x;
    A[t] = pfx[t]; A[t + 1024] = pfx[t + 1024];
    __syncthreads();
    int* src = A; int* dst = B;
    for (int off = 1; off < 2048; off <<= 1) {
        dst[t]        = src[t]        + (t >= off ? src[t - off] : 0);
        dst[t + 1024] = src[t + 1024] + src[t + 1024 - off];
        __syncthreads();
        int* tmp = src; src = dst; dst = tmp;
    }
    pfx[t]        = t ? src[t - 1] : 0;
    pfx[t + 1024] = src[t + 1023];
}

// K4: relabel cells in spatial order; idx_map[cell] <- new id; oldof[new] = old id
__global__ __launch_bounds__(1024) void relabel_kernel(const int* __restrict__ pfx,
                                                       int* __restrict__ idx_map,
                                                       int* __restrict__ oldof) {
    __shared__ int wsum[16];
    int i = blockIdx.x * 1024 + threadIdx.x;
    int old = idx_map[i];
    int bit = old >= 0 ? 1 : 0;
    unsigned long long m = __ballot(bit);
    int lane = threadIdx.x & 63, wave = threadIdx.x >> 6;
    int intra = __popcll(m & ((1ull << lane) - 1ull));
    if (lane == 0) wsum[wave] = __popcll(m);
    __syncthreads();
    int woff = 0;
    for (int w = 0; w < wave; ++w) woff += wsum[w];
    if (bit) {
        int nid = pfx[blockIdx.x] + woff + intra;
        idx_map[i] = nid;
        oldof[nid] = old;
    }
}

// K5: fused prep — feats permuted f32->bf16 (+zero row); W [125][ci][co] f32 ->
// XOR-swizzled [125][co][ci] bf16 LDS image: 16B chunk c of row co lands at c^(co&7),
// so conv's afrag ds_read_b128 spreads 8 lanes/bank-quad (= b128 floor, no conflicts).
__global__ __launch_bounds__(256) void prep_kernel(const float* __restrict__ Wt,
                                                   const float* __restrict__ feats,
                                                   const int* __restrict__ oldof,
                                                   unsigned short* __restrict__ wt,
                                                   unsigned short* __restrict__ fb) {
    int i = blockIdx.x * 256 + threadIdx.x;
    if (i < F16N) {
        int p = i >> 4, c = i & 15;
        int old = oldof[p];
        f32x4 f = *(const f32x4*)(feats + (size_t)old * 64 + c * 4);
        u16x4 u;
        u[0] = f2bf(f[0]); u[1] = f2bf(f[1]); u[2] = f2bf(f[2]); u[3] = f2bf(f[3]);
        *(u16x4*)(fb + (size_t)i * 4) = u;
    } else if (i < F16N + 16) {
        *(u16x4*)(fb + (size_t)i * 4) = (u16x4)0;
    } else if (i < PREP_N) {
        int j = i - (F16N + 16);
        int k = j >> 12, r = j & 4095;
        int co = r >> 6, ci = r & 63;
        int dst = (co << 6) | ((((ci >> 3) ^ (co & 7)) << 3) | (ci & 7));
        wt[(k << 12) + dst] = f2bf(Wt[(k << 12) + (ci << 6) + co]);
    }
}

// stage one 8KB W slice into LDS slot: 256 threads x 2 x 16B, wave-contiguous
static __device__ __forceinline__ void stage_w(const unsigned short* wt, int k,
                                               unsigned short* dst, int tid) {
    const unsigned short* src = wt + ((size_t)k << 12) + tid * 8;
    __builtin_amdgcn_global_load_lds((const uint_as1*)(const void*)src,
                                     (uint_as3*)(void*)(dst + tid * 8), 16, 0, 0);
    __builtin_amdgcn_global_load_lds((const uint_as1*)(const void*)(src + 2048),
                                     (uint_as3*)(void*)(dst + tid * 8 + 2048), 16, 0, 0);
}

// Conv over spatially-relabeled voxels. Block = 256 consecutive (spatial) voxels,
// XCD-swizzled so each XCD owns a contiguous label slab (L2-resident window).
// K-loop in 25 groups of 5 (fixed dz,dy; dx=-2..2): per group, stage 5 W slices +
// probe 5 consecutive idx_map cells, ONE barrier, then 5 k's of barrier-free
// MFMA compute (160 MFMA/wave) with per-16-voxel zero-column skip (~20%).
__global__ __launch_bounds__(256, 3) void conv_kernel(
    const int* __restrict__ coords, const unsigned short* __restrict__ fb,
    const unsigned short* __restrict__ wt, const int* __restrict__ idx_map,
    const int* __restrict__ oldof,
    float* __restrict__ out, float* __restrict__ stats) {
    __shared__ unsigned short lds_w[KG * 4096];   // 40 KB, 5 slices
    __shared__ int lds_nbr[KG * 256];             // 5 KB, transposed [kk][w][l15][t]

    const int vblk = (blockIdx.x & 7) * 98 + (blockIdx.x >> 3);
    const int vbase = vblk * 256;
    if (vbase >= NVOX) return;

    const int tid  = threadIdx.x;
    const int wave = tid >> 6;
    const int lane = tid & 63;
    const int g    = lane >> 4;
    const int l15  = lane & 15;
    const int vox  = vbase + tid;
    const bool live = vox < NVOX;

    int z = 0, y = 0, x = 0;
    if (live) {
        int old = oldof[vox];
        z = coords[old * 3 + 0]; y = coords[old * 3 + 1]; x = coords[old * 3 + 2];
    }
    const int slot = (tid & ~63) | ((tid & 15) << 2) | ((tid >> 4) & 3);
    const int sw0 = ((g    ) ^ (l15 & 7)) << 4;   // swizzled chunk offset, s=0
    const int sw1 = ((g + 4) ^ (l15 & 7)) << 4;   // s=1

    f32x4 acc[4][4];
#pragma unroll
    for (int a = 0; a < 4; ++a)
#pragma unroll
        for (int b = 0; b < 4; ++b) acc[a][b] = (f32x4)0.0f;

    const char* fbp = (const char*)fb;

    for (int grp = 0; grp < NK / KG; ++grp) {
        __syncthreads();                          // prev group's readers done
        // stage this group's 5 W slices
#pragma unroll
        for (int kk = 0; kk < KG; ++kk)
            stage_w(wt, grp * KG + kk, &lds_w[kk * 4096], tid);
        // probe 5 consecutive cells: dz,dy fixed per group, dx = -2..2
        const int dz = grp / 5 - 2, dy = grp % 5 - 2;
        const int nz = z + dz, ny = y + dy;
        const bool rowok = live && ((unsigned)nz < 128u) && ((unsigned)ny < 128u);
        const int base = (nz << 14) | (ny << 7);
#pragma unroll
        for (int kk = 0; kk < KG; ++kk) {
            int nx = x + kk - 2;
            int j = NVOX;
            if (rowok && ((unsigned)nx < 128u)) {
                int t = idx_map[base | nx];
                if (t >= 0) j = t;
            }
            lds_nbr[kk * 256 + slot] = j;
        }
        __syncthreads();                          // stage + nbr visible

        for (int kk = 0; kk < KG; ++kk) {
            int4 jt4 = *(const int4*)&lds_nbr[kk * 256 + wave * 64 + l15 * 4];
            const int jt[4] = {jt4.x, jt4.y, jt4.z, jt4.w};
            const char* wb = (const char*)&lds_w[kk * 4096];

            bf16x8 af0[4], af1[4];
#pragma unroll
            for (int a = 0; a < 4; ++a) {
                af0[a] = *(const bf16x8*)(wb + (((a * 16 + l15) << 7) | sw0));
                af1[a] = *(const bf16x8*)(wb + (((a * 16 + l15) << 7) | sw1));
            }
#pragma unroll
            for (int t = 0; t < 4; ++t) {
                if (__any(jt[t] != NVOX)) {       // wave-uniform zero-column skip
                    const char* rp = fbp + ((size_t)(unsigned)jt[t] << 7) + (g << 4);
                    bf16x8 b0 = *(const bf16x8*)(rp);
                    bf16x8 b1 = *(const bf16x8*)(rp + 64);
#pragma unroll
                    for (int a = 0; a < 4; ++a) {
                        acc[a][t] = __builtin_amdgcn_mfma_f32_16x16x32_bf16(af0[a], b0, acc[a][t], 0, 0, 0);
                        acc[a][t] = __builtin_amdgcn_mfma_f32_16x16x32_bf16(af1[a], b1, acc[a][t], 0, 0, 0);
                    }
                }
            }
        }
    }

    // epilogue: scatter rows back to ORIGINAL voxel order (bias cancels under BN)
#pragma unroll
    for (int b = 0; b < 4; ++b) {
        int v = vbase + wave * 64 + b * 16 + l15;
        if (v < NVOX) {
            int o = oldof[v];
#pragma unroll
            for (int a = 0; a < 4; ++a)
                *(f32x4*)(out + (size_t)o * 64 + a * 16 + g * 4) = acc[a][b];
        }
    }

    // BN batch-stat partials over this wave's 64 voxels
    float s1[16], s2[16];
#pragma unroll
    for (int a = 0; a < 4; ++a)
#pragma unroll
        for (int r = 0; r < 4; ++r) {
            float s = 0.f, q = 0.f;
#pragma unroll
            for (int b = 0; b < 4; ++b) { float xv = acc[a][b][r]; s += xv; q += xv * xv; }
            s1[a * 4 + r] = s; s2[a * 4 + r] = q;
        }
#pragma unroll
    for (int m = 1; m < 16; m <<= 1) {
#pragma unroll
        for (int i = 0; i < 16; ++i) {
            s1[i] += __shfl_xor(s1[i], m, 64);
            s2[i] += __shfl_xor(s2[i], m, 64);
        }
    }
    if (l15 == 0) {
#pragma unroll
        for (int a = 0; a < 4; ++a)
#pragma unroll
            for (int r = 0; r < 4; ++r) {
                int co = a * 16 + g * 4 + r;
                atomicAdd(&stats[co],      s1[a * 4 + r]);
                atomicAdd(&stats[64 + co], s2[a * 4 + r]);
            }
    }
}

__global__ __launch_bounds__(256) void finalize_kernel(float* __restrict__ out,
                                                       const float* __restrict__ stats,
                                                       const float* __restrict__ gamma,
                                                       const float* __restrict__ beta) {
    int i = blockIdx.x * 256 + threadIdx.x;
    if (i >= NVOX * 16) return;
    int cg = (i & 15) * 4;
    f32x4 v = *(f32x4*)(out + (size_t)i * 4);
    f32x4 r;
#pragma unroll
    for (int c = 0; c < 4; ++c) {
        int co = cg + c;
        float mean = stats[co] * (1.0f / NVOX);
        float var  = stats[64 + co] * (1.0f / NVOX) - mean * mean;
        float sc   = rsqrtf(var + 1e-5f) * gamma[co];
        float sh   = beta[co] - mean * sc;
        float yv   = v[c] * sc + sh;
        r[c] = yv > 0.f ? yv : expm1f(yv);
    }
    *(f32x4*)(out + (size_t)i * 4) = r;
}

extern "C" void kernel_launch(void* const* d_in, const int* in_sizes, int n_in,
                              void* d_out, int out_size, void* d_ws, size_t ws_size,
                              hipStream_t stream) {
    const float* feats  = (const float*)d_in[0];
    const int*   coords = (const int*)d_in[1];
    const float* Wt     = (const float*)d_in[2];
    // d_in[3] = bias: unused — cancels exactly under training-mode BN
    const float* gamma  = (const float*)d_in[4];
    const float* beta   = (const float*)d_in[5];
    float* out = (float*)d_out;
    char*  ws  = (char*)d_ws;

    unsigned short* wt  = (unsigned short*)(ws + WT_OFF);
    float* stats        = (float*)(ws + STATS_OFF);
    int*   pfx          = (int*)(ws + PFX_OFF);
    int*   oldof        = (int*)(ws + OLD_OFF);
    unsigned short* fb  = (unsigned short*)(ws + FB_OFF);
    int*   idx_map      = (int*)(ws + IDX_OFF);

    hipMemsetAsync(idx_map, 0xFF, (size_t)GRID_LIN * 4, stream);  // -1
    hipMemsetAsync(stats, 0, 128 * 4, stream);

    scatter_kernel<<<(NVOX + 255) / 256, 256, 0, stream>>>(coords, idx_map);
    count_kernel<<<GRID_LIN / 1024, 1024, 0, stream>>>(idx_map, pfx);
    scan_kernel<<<1, 1024, 0, stream>>>(pfx);
    relabel_kernel<<<GRID_LIN / 1024, 1024, 0, stream>>>(pfx, idx_map, oldof);
    prep_kernel<<<(PREP_N + 255) / 256, 256, 0, stream>>>(Wt, feats, oldof, wt, fb);
    conv_kernel<<<784, 256, 0, stream>>>(coords, fb, wt, idx_map, oldof, out, stats);
    finalize_kernel<<<12500, 256, 0, stream>>>(out, stats, gamma, beta);
}